// Round 18
// baseline (108.767 us; speedup 1.0000x reference)
//
#include <hip/hip_runtime.h>
#include <stdint.h>

typedef _Float16 f16;
typedef _Float16 f16x8 __attribute__((ext_vector_type(8)));
typedef float f32x4 __attribute__((ext_vector_type(4)));
typedef float f32x16 __attribute__((ext_vector_type(16)));

typedef const __attribute__((address_space(1))) void* gas_ptr;
typedef __attribute__((address_space(3))) void* las_ptr;

__device__ __forceinline__ void gload16(const void* g, void* l) {
  __builtin_amdgcn_global_load_lds((gas_ptr)g, (las_ptr)l, 16, 0, 0);
}

// ws layout (bytes)
#define OFF_A16 0u              // [8192][2048] f16  (x1_att rows 0..4095, x2_att rows 4096..8191)
#define OFF_W16 33554432u       // [1024][2048] f16
#define OFF_K16 37748736u       // keys [8192][1024] f16
#define OFF_VT  54525952u       // V^T  [8][8][128][512] f16
#define WS_NEED 62914560u

// ---------------- kernel 1: prep = V^T transpose (blocks 0..255) + f32->f16 convert ----------------
__global__ void k_prep(const float* __restrict__ x1a, const float* __restrict__ x2a,
                       const float* __restrict__ x2, const float* __restrict__ W,
                       f16* __restrict__ A16, f16* __restrict__ W16, f16* __restrict__ VT) {
  __shared__ f16 T[128 * 130];  // used only by transpose blocks
  int t = threadIdx.x;
  if (blockIdx.x < 256) {
    // V^T: VT[((b*8+n)*128 + d)*512 + k] = (f16) x2[(b*512+k)*1024 + n*128 + d]
    int bid = blockIdx.x;
    int kt = bid & 3, n = (bid >> 2) & 7, b = bid >> 5;
    int k0 = kt * 128;
    #pragma unroll
    for (int p = 0; p < 16; ++p) {
      int kl = p * 8 + (t >> 5);
      int c4 = t & 31;
      float4 v = *(const float4*)(x2 + (size_t)(b * 512 + k0 + kl) * 1024 + n * 128 + c4 * 4);
      int d0 = c4 * 4;
      T[(d0 + 0) * 130 + kl] = (f16)v.x;
      T[(d0 + 1) * 130 + kl] = (f16)v.y;
      T[(d0 + 2) * 130 + kl] = (f16)v.z;
      T[(d0 + 3) * 130 + kl] = (f16)v.w;
    }
    __syncthreads();
    #pragma unroll
    for (int p = 0; p < 8; ++p) {
      int d = p * 16 + (t >> 4);
      int c = t & 15;
      f16x8 h;
      #pragma unroll
      for (int j = 0; j < 8; ++j) h[j] = T[d * 130 + c * 8 + j];
      *(f16x8*)(VT + (size_t)((b * 8 + n) * 128 + d) * 512 + k0 + c * 8) = h;
    }
    return;
  }
  // convert: 8 f32 -> 8 f16 per thread-iter, grid-stride over remaining blocks
  const int NA = (8192 * 2048) / 8;  // 2097152
  const int NH = NA / 2;
  const int NW = (1024 * 2048) / 8;  // 262144
  const int NT = NA + NW;
  int stride = (gridDim.x - 256) * blockDim.x;
  for (int g = (blockIdx.x - 256) * blockDim.x + t; g < NT; g += stride) {
    const float* src;
    f16* dst;
    if (g < NA) {
      src = (g < NH) ? (x1a + 8 * (size_t)g) : (x2a + 8 * (size_t)(g - NH));
      dst = A16 + 8 * (size_t)g;
    } else {
      src = W + 8 * (size_t)(g - NA);
      dst = W16 + 8 * (size_t)(g - NA);
    }
    float4 v0 = *(const float4*)src;
    float4 v1 = *(const float4*)(src + 4);
    f16x8 h;
    h[0] = (f16)v0.x; h[1] = (f16)v0.y; h[2] = (f16)v0.z; h[3] = (f16)v0.w;
    h[4] = (f16)v1.x; h[5] = (f16)v1.y; h[6] = (f16)v1.z; h[7] = (f16)v1.w;
    *(f16x8*)dst = h;
  }
}

// ---------------- kernel 2: keys = relu(A @ W^T) [*final_v for x2 rows] ----------------
// 128x128 tile, BK=128, LDS DOUBLE-buffered (128KB, 1 block/CU) with COUNTED
// vmcnt (T4, m218): STAGE(t+1) issues into buf^1, then s_waitcnt vmcnt(16)
// (waits only buf[cur]'s 16 loads; the 16 new ones stay in flight ACROSS the
// barrier), raw s_barrier, ds_read+MFMA, s_barrier.  Never vmcnt(0) mid-loop.
// Swizzle/read pattern identical to R10 (verified conflict-free).
__global__ void __launch_bounds__(256)
k_gemm_keys(const f16* __restrict__ A16, const f16* __restrict__ W16,
            const float* __restrict__ final_v, f16* __restrict__ K16) {
  __shared__ f16 Alds[2 * 128 * 128];
  __shared__ f16 Wlds[2 * 128 * 128];
  int bid = blockIdx.x;
  int sw = (bid & 7) * 64 + (bid >> 3);  // XCD swizzle (512 % 8 == 0, bijective)
  int mt = sw >> 3, nt = sw & 7;
  int t = threadIdx.x, l = t & 63, w = t >> 6;
  int wm = w >> 1, wn = w & 1;
  f32x16 acc[2][2];
  #pragma unroll
  for (int i = 0; i < 2; ++i)
    #pragma unroll
    for (int j = 0; j < 2; ++j)
      #pragma unroll
      for (int r = 0; r < 16; ++r) acc[i][j][r] = 0.f;
  const char* Ab = (const char*)A16 + (size_t)mt * 128 * 4096;
  const char* Wb = (const char*)W16 + (size_t)nt * 128 * 4096;
  size_t soff[8];
  #pragma unroll
  for (int i = 0; i < 8; ++i) {
    int row = (w * 8 + i) * 4 + (l >> 4);
    soff[i] = (size_t)row * 4096 + (((l & 15) ^ (row & 15)) << 4);
  }
  int g8 = l >> 5;
  int rowA = wm * 64 + (l & 31);
  int rowB = wn * 64 + (l & 31);
  int sA = rowA & 15, sB = rowB & 15;

#define GSTAGE(bufsel, ksv) do {                                               \
    int k0b_ = (ksv) * 256;                                                    \
    char* abase_ = (char*)Alds + (bufsel) * 32768;                             \
    char* wbase_ = (char*)Wlds + (bufsel) * 32768;                             \
    _Pragma("unroll")                                                          \
    for (int i_ = 0; i_ < 8; ++i_) {                                           \
      gload16(Ab + soff[i_] + k0b_, abase_ + (w * 8 + i_) * 1024);             \
      gload16(Wb + soff[i_] + k0b_, wbase_ + (w * 8 + i_) * 1024);             \
    }                                                                          \
  } while (0)

  GSTAGE(0, 0);
  int cur = 0;
  for (int ks = 0; ks < 16; ++ks) {
    if (ks < 15) {
      GSTAGE(cur ^ 1, ks + 1);
      asm volatile("s_waitcnt vmcnt(16)" ::: "memory");  // buf[cur] landed; 16 new in flight
    } else {
      asm volatile("s_waitcnt vmcnt(0)" ::: "memory");   // tail: drain last stage
    }
    __builtin_amdgcn_s_barrier();   // all waves' stage of buf[cur] complete
    const char* rdA0 = (const char*)Alds + cur * 32768 + rowA * 256;
    const char* rdB0 = (const char*)Wlds + cur * 32768 + rowB * 256;
    f16x8 af[2][8], bf[2][8];
    #pragma unroll
    for (int mi = 0; mi < 2; ++mi)
      #pragma unroll
      for (int ks2 = 0; ks2 < 8; ++ks2) {
        af[mi][ks2] = *(const f16x8*)(rdA0 + mi * 8192 + (((ks2 * 2 + g8) ^ sA) << 4));
        bf[mi][ks2] = *(const f16x8*)(rdB0 + mi * 8192 + (((ks2 * 2 + g8) ^ sB) << 4));
      }
    #pragma unroll
    for (int ks2 = 0; ks2 < 8; ++ks2)
      #pragma unroll
      for (int mi = 0; mi < 2; ++mi)
        #pragma unroll
        for (int ni = 0; ni < 2; ++ni)
          acc[mi][ni] = __builtin_amdgcn_mfma_f32_32x32x16_f16(af[mi][ks2], bf[ni][ks2], acc[mi][ni], 0, 0, 0);
    __builtin_amdgcn_s_barrier();   // all reads of buf[cur] done before it is re-staged
    cur ^= 1;
  }
#undef GSTAGE
  // epilogue: C/D layout col=lane&31, row=(reg&3)+8*(reg>>2)+4*(lane>>5)
  bool isx2 = (mt >= 32);
  int c = l & 31, r2 = l >> 5;
  #pragma unroll
  for (int ni = 0; ni < 2; ++ni) {
    int col = nt * 128 + wn * 64 + ni * 32 + c;
    float fvv = isx2 ? final_v[col] : 1.0f;
    #pragma unroll
    for (int mi = 0; mi < 2; ++mi) {
      int rowbase = mt * 128 + wm * 64 + mi * 32 + 4 * r2;
      #pragma unroll
      for (int r = 0; r < 16; ++r) {
        int row = rowbase + (r & 3) + 8 * (r >> 2);
        K16[(size_t)row * 1024 + col] = (f16)(fmaxf(acc[mi][ni][r], 0.f) * fvv);
      }
    }
  }
}

// ---------------- kernel 3: flash attention per (b, level, 64-row q tile) ----------------
// K/V double-buffered in LDS, ONE barrier per kt. Q direct global->reg.  [R12-verified]
__global__ void __launch_bounds__(256)
k_attn(const f16* __restrict__ K16, const f16* __restrict__ VT,
       const int* __restrict__ mask, float* __restrict__ out) {
  __shared__ f16 Klds[2 * 64 * 128];
  __shared__ f16 Vlds[2 * 128 * 64];
  __shared__ f16 Plds[4 * 16 * 64];
  __shared__ float bias[512];
  int bid = blockIdx.x;
  int qt = bid & 7, n = (bid >> 3) & 7, b = bid >> 6;
  int t = threadIdx.x, l = t & 63, w = t >> 6;
  for (int i = t; i < 512; i += 256) bias[i] = mask[b * 512 + i] ? -1e30f : 0.0f;
  int r4 = l >> 4;
  int slot = (l & 15) << 4;
  int lg = r4 << 4;
  const char* Kg = (const char*)K16 + ((size_t)(4096 + b * 512) * 1024 + n * 128) * 2;
  const char* Vg = (const char*)VT + (size_t)((b * 8 + n) * 128) * 1024;
  int vr = l >> 3;
  int vslot = (l & 7) << 4;

#define STAGE_KV(ktv, bufsel) do {                                              \
    _Pragma("unroll")                                                           \
    for (int i_ = 0; i_ < 4; ++i_) {                                            \
      int rl_ = w * 16 + i_ * 4 + r4;                                           \
      gload16(Kg + (size_t)((ktv) * 64 + rl_) * 2048 + (slot ^ ((rl_ & 7) << 4)), \
              (char*)Klds + (bufsel) * 16384 + (w * 16 + i_ * 4) * 256);        \
    }                                                                           \
    _Pragma("unroll")                                                           \
    for (int i_ = 0; i_ < 4; ++i_) {                                            \
      int dl_ = w * 32 + i_ * 8 + vr;                                           \
      gload16(Vg + (size_t)dl_ * 1024 + (ktv) * 128 + (vslot ^ ((dl_ & 7) << 4)), \
              (char*)Vlds + (bufsel) * 16384 + (w * 32 + i_ * 8) * 128);        \
    }                                                                           \
  } while (0)

  // Q fragments direct from global: frag kk = level-slice bytes [kk*64+lg, +16)
  const char* Qg = (const char*)K16 + ((size_t)(b * 512 + qt * 64) * 1024 + n * 128) * 2;
  int qrow = w * 16 + (l & 15);
  f16x8 qf[4];
  #pragma unroll
  for (int kk = 0; kk < 4; ++kk)
    qf[kk] = *(const f16x8*)(Qg + (size_t)qrow * 2048 + kk * 64 + lg);
  f32x4 o[8];
  #pragma unroll
  for (int dt = 0; dt < 8; ++dt) { o[dt][0] = 0.f; o[dt][1] = 0.f; o[dt][2] = 0.f; o[dt][3] = 0.f; }
  float m_r[4], l_r[4];
  #pragma unroll
  for (int r = 0; r < 4; ++r) { m_r[r] = -1e30f; l_r[r] = 0.0f; }
  char* Pw = (char*)Plds + w * 2048;

  STAGE_KV(0, 0);
  __syncthreads();  // drains stage(0); also orders bias[] init
  #pragma unroll 8
  for (int kt = 0; kt < 8; ++kt) {
    int cur = kt & 1;
    if (kt < 7) STAGE_KV(kt + 1, cur ^ 1);  // overlaps with compute below
    const char* Kl = (const char*)Klds + cur * 16384;
    const char* Vl = (const char*)Vlds + cur * 16384;
    f32x4 s[4];
    #pragma unroll
    for (int nt4 = 0; nt4 < 4; ++nt4) {
      s[nt4][0] = 0.f; s[nt4][1] = 0.f; s[nt4][2] = 0.f; s[nt4][3] = 0.f;
      int krow = nt4 * 16 + (l & 15);
      int ksz = (krow & 7) << 4;
      #pragma unroll
      for (int kk = 0; kk < 4; ++kk) {
        f16x8 kf = *(const f16x8*)(Kl + krow * 256 + ((kk * 64 + lg) ^ ksz));
        s[nt4] = __builtin_amdgcn_mfma_f32_16x16x32_f16(qf[kk], kf, s[nt4], 0, 0, 0);
      }
      float bc = bias[kt * 64 + nt4 * 16 + (l & 15)];
      #pragma unroll
      for (int r = 0; r < 4; ++r) s[nt4][r] += bc;
    }
    float pmax[4], scale[4], csum[4];
    #pragma unroll
    for (int r = 0; r < 4; ++r)
      pmax[r] = fmaxf(fmaxf(s[0][r], s[1][r]), fmaxf(s[2][r], s[3][r]));
    #pragma unroll
    for (int off = 1; off <= 8; off <<= 1) {
      #pragma unroll
      for (int r = 0; r < 4; ++r) pmax[r] = fmaxf(pmax[r], __shfl_xor(pmax[r], off));
    }
    #pragma unroll
    for (int r = 0; r < 4; ++r) {
      float mn = fmaxf(m_r[r], pmax[r]);
      scale[r] = __expf(m_r[r] - mn);
      m_r[r] = mn;
      csum[r] = 0.0f;
    }
    #pragma unroll
    for (int nt4 = 0; nt4 < 4; ++nt4) {
      #pragma unroll
      for (int r = 0; r < 4; ++r) {
        float sv = s[nt4][r];
        float p = (sv <= -1e29f) ? 0.0f : __expf(sv - m_r[r]);
        csum[r] += p;
        int prow = (r4 << 2) + r;
        int addr = prow * 128 + (((nt4 * 16 + (l & 15)) * 2) ^ ((prow & 7) << 4));
        *(f16*)(Pw + addr) = (f16)p;
      }
    }
    #pragma unroll
    for (int off = 1; off <= 8; off <<= 1) {
      #pragma unroll
      for (int r = 0; r < 4; ++r) csum[r] += __shfl_xor(csum[r], off);
    }
    #pragma unroll
    for (int r = 0; r < 4; ++r) l_r[r] = l_r[r] * scale[r] + csum[r];
    #pragma unroll
    for (int dt = 0; dt < 8; ++dt) {
      #pragma unroll
      for (int r = 0; r < 4; ++r) o[dt][r] *= scale[r];
    }
    asm volatile("s_waitcnt lgkmcnt(0)" ::: "memory");  // P writes visible to own-wave reads
    int prow = l & 15;
    int psz = (prow & 7) << 4;
    f16x8 pf0 = *(const f16x8*)((const char*)Pw + prow * 128 + (lg ^ psz));
    f16x8 pf1 = *(const f16x8*)((const char*)Pw + prow * 128 + ((lg + 64) ^ psz));
    #pragma unroll
    for (int dt = 0; dt < 8; ++dt) {
      int drow = dt * 16 + (l & 15);
      int dsz = (drow & 7) << 4;
      f16x8 vf0 = *(const f16x8*)(Vl + drow * 128 + (lg ^ dsz));
      f16x8 vf1 = *(const f16x8*)(Vl + drow * 128 + ((lg + 64) ^ dsz));
      o[dt] = __builtin_amdgcn_mfma_f32_16x16x32_f16(pf0, vf0, o[dt], 0, 0, 0);
      o[dt] = __builtin_amdgcn_mfma_f32_16x16x32_f16(pf1, vf1, o[dt], 0, 0, 0);
    }
    __syncthreads();
  }
#undef STAGE_KV
  size_t ob = (size_t)(b * 512 + qt * 64 + w * 16 + (r4 << 2)) * 1024 + n * 128 + (l & 15);
  #pragma unroll
  for (int r = 0; r < 4; ++r) {
    float inv = 1.0f / fmaxf(l_r[r], 1e-30f);
    #pragma unroll
    for (int dt = 0; dt < 8; ++dt)
      out[ob + (size_t)r * 1024 + dt * 16] = o[dt][r] * inv;
  }
}

extern "C" void kernel_launch(void* const* d_in, const int* in_sizes, int n_in,
                              void* d_out, int out_size, void* d_ws, size_t ws_size,
                              hipStream_t stream) {
  const float* x1a = (const float*)d_in[0];
  const float* x2a = (const float*)d_in[1];
  const float* x2  = (const float*)d_in[2];
  const int*   msk = (const int*)d_in[3];
  const float* W   = (const float*)d_in[4];
  const float* fv  = (const float*)d_in[5];
  float* out = (float*)d_out;
  if (ws_size < (size_t)WS_NEED) return;  // ws too small: fail loudly via unmodified (poisoned) d_out
  char* ws = (char*)d_ws;
  f16* A16 = (f16*)(ws + OFF_A16);
  f16* W16 = (f16*)(ws + OFF_W16);
  f16* K16 = (f16*)(ws + OFF_K16);
  f16* VT  = (f16*)(ws + OFF_VT);
  k_prep<<<2304, 256, 0, stream>>>(x1a, x2a, x2, W, A16, W16, VT);
  k_gemm_keys<<<512, 256, 0, stream>>>(A16, W16, fv, K16);
  k_attn<<<512, 256, 0, stream>>>(K16, VT, msk, out);
}

// Round 19
// 97.385 us; speedup vs baseline: 1.1169x; 1.1169x over previous
//
#include <hip/hip_runtime.h>
#include <stdint.h>

typedef _Float16 f16;
typedef _Float16 f16x8 __attribute__((ext_vector_type(8)));
typedef float f32x4 __attribute__((ext_vector_type(4)));
typedef float f32x16 __attribute__((ext_vector_type(16)));

typedef const __attribute__((address_space(1))) void* gas_ptr;
typedef __attribute__((address_space(3))) void* las_ptr;

__device__ __forceinline__ void gload16(const void* g, void* l) {
  __builtin_amdgcn_global_load_lds((gas_ptr)g, (las_ptr)l, 16, 0, 0);
}

// ws layout (bytes)
#define OFF_A16 0u              // [8192][2048] f16  (x1_att rows 0..4095, x2_att rows 4096..8191)
#define OFF_W16 33554432u       // [1024][2048] f16
#define OFF_K16 37748736u       // keys [8192][1024] f16
#define OFF_VT  54525952u       // V^T  [8][8][128][512] f16
#define WS_NEED 62914560u

// ---------------- kernel 1: prep = V^T transpose (blocks 0..255) + f32->f16 convert ----------------
__global__ void k_prep(const float* __restrict__ x1a, const float* __restrict__ x2a,
                       const float* __restrict__ x2, const float* __restrict__ W,
                       f16* __restrict__ A16, f16* __restrict__ W16, f16* __restrict__ VT) {
  __shared__ f16 T[128 * 130];  // used only by transpose blocks
  int t = threadIdx.x;
  if (blockIdx.x < 256) {
    // V^T: VT[((b*8+n)*128 + d)*512 + k] = (f16) x2[(b*512+k)*1024 + n*128 + d]
    int bid = blockIdx.x;
    int kt = bid & 3, n = (bid >> 2) & 7, b = bid >> 5;
    int k0 = kt * 128;
    #pragma unroll
    for (int p = 0; p < 16; ++p) {
      int kl = p * 8 + (t >> 5);
      int c4 = t & 31;
      float4 v = *(const float4*)(x2 + (size_t)(b * 512 + k0 + kl) * 1024 + n * 128 + c4 * 4);
      int d0 = c4 * 4;
      T[(d0 + 0) * 130 + kl] = (f16)v.x;
      T[(d0 + 1) * 130 + kl] = (f16)v.y;
      T[(d0 + 2) * 130 + kl] = (f16)v.z;
      T[(d0 + 3) * 130 + kl] = (f16)v.w;
    }
    __syncthreads();
    #pragma unroll
    for (int p = 0; p < 8; ++p) {
      int d = p * 16 + (t >> 4);
      int c = t & 15;
      f16x8 h;
      #pragma unroll
      for (int j = 0; j < 8; ++j) h[j] = T[d * 130 + c * 8 + j];
      *(f16x8*)(VT + (size_t)((b * 8 + n) * 128 + d) * 512 + k0 + c * 8) = h;
    }
    return;
  }
  // convert: 8 f32 -> 8 f16 per thread-iter, grid-stride over remaining blocks
  const int NA = (8192 * 2048) / 8;  // 2097152
  const int NH = NA / 2;
  const int NW = (1024 * 2048) / 8;  // 262144
  const int NT = NA + NW;
  int stride = (gridDim.x - 256) * blockDim.x;
  for (int g = (blockIdx.x - 256) * blockDim.x + t; g < NT; g += stride) {
    const float* src;
    f16* dst;
    if (g < NA) {
      src = (g < NH) ? (x1a + 8 * (size_t)g) : (x2a + 8 * (size_t)(g - NH));
      dst = A16 + 8 * (size_t)g;
    } else {
      src = W + 8 * (size_t)(g - NA);
      dst = W16 + 8 * (size_t)(g - NA);
    }
    float4 v0 = *(const float4*)src;
    float4 v1 = *(const float4*)(src + 4);
    f16x8 h;
    h[0] = (f16)v0.x; h[1] = (f16)v0.y; h[2] = (f16)v0.z; h[3] = (f16)v0.w;
    h[4] = (f16)v1.x; h[5] = (f16)v1.y; h[6] = (f16)v1.z; h[7] = (f16)v1.w;
    *(f16x8*)dst = h;
  }
}

// ---------------- kernel 2: keys = relu(A @ W^T) [*final_v for x2 rows] ----------------
// 128x128 tile, BK=64, LDS double-buffer 64KB (keeps 2 blocks/CU) + COUNTED
// vmcnt(8) + raw s_barrier: isolates T4 drain-removal at CONSTANT occupancy
// (R18's BK=128 dbuf halved occupancy and lost).  Stage/read mapping = R8's
// verified BK=64 set (8-slot XOR; ~4-way read conflicts measured ~free here).
__global__ void __launch_bounds__(256)
k_gemm_keys(const f16* __restrict__ A16, const f16* __restrict__ W16,
            const float* __restrict__ final_v, f16* __restrict__ K16) {
  __shared__ f16 Alds[2 * 128 * 64];
  __shared__ f16 Wlds[2 * 128 * 64];
  int bid = blockIdx.x;
  int sw = (bid & 7) * 64 + (bid >> 3);  // XCD swizzle (512 % 8 == 0, bijective)
  int mt = sw >> 3, nt = sw & 7;
  int t = threadIdx.x, l = t & 63, w = t >> 6;
  int wm = w >> 1, wn = w & 1;
  f32x16 acc[2][2];
  #pragma unroll
  for (int i = 0; i < 2; ++i)
    #pragma unroll
    for (int j = 0; j < 2; ++j)
      #pragma unroll
      for (int r = 0; r < 16; ++r) acc[i][j][r] = 0.f;
  const char* Ab = (const char*)A16 + (size_t)mt * 128 * 4096;
  const char* Wb = (const char*)W16 + (size_t)nt * 128 * 4096;
  int lr = l >> 3;                         // stage row within 8-row issue
  int sslot = ((l & 7) << 4) ^ (lr << 4);  // pre-swizzled global source slot
  int g8 = l >> 5;
  int rowA = wm * 64 + (l & 31);
  int rowB = wn * 64 + (l & 31);
  int sA = (rowA & 7) << 4, sB = (rowB & 7) << 4;

#define GSTAGE(bufsel, ksv) do {                                               \
    int k0b_ = (ksv) * 128;                                                    \
    char* abase_ = (char*)Alds + (bufsel) * 16384;                             \
    char* wbase_ = (char*)Wlds + (bufsel) * 16384;                             \
    _Pragma("unroll")                                                          \
    for (int i_ = 0; i_ < 4; ++i_) {                                           \
      int rl_ = w * 32 + i_ * 8 + lr;                                          \
      gload16(Ab + (size_t)rl_ * 4096 + k0b_ + sslot, abase_ + (w * 4 + i_) * 1024); \
      gload16(Wb + (size_t)rl_ * 4096 + k0b_ + sslot, wbase_ + (w * 4 + i_) * 1024); \
    }                                                                          \
  } while (0)

  GSTAGE(0, 0);
  int cur = 0;
  for (int ks = 0; ks < 32; ++ks) {
    if (ks < 31) {
      GSTAGE(cur ^ 1, ks + 1);
      asm volatile("s_waitcnt vmcnt(8)" ::: "memory");  // buf[cur]'s 8 landed; 8 new in flight
    } else {
      asm volatile("s_waitcnt vmcnt(0)" ::: "memory");  // tail: drain last stage
    }
    __builtin_amdgcn_s_barrier();   // all waves' stage of buf[cur] complete
    const char* Al = (const char*)Alds + cur * 16384;
    const char* Wl = (const char*)Wlds + cur * 16384;
    f16x8 af[2][4], bf[2][4];
    #pragma unroll
    for (int mi = 0; mi < 2; ++mi) {
      int ra = rowA + mi * 32;
      int rb = rowB + mi * 32;
      #pragma unroll
      for (int ks2 = 0; ks2 < 4; ++ks2) {
        af[mi][ks2] = *(const f16x8*)(Al + ra * 128 + ((ks2 * 32 + g8 * 16) ^ sA));
        bf[mi][ks2] = *(const f16x8*)(Wl + rb * 128 + ((ks2 * 32 + g8 * 16) ^ sB));
      }
    }
    #pragma unroll
    for (int ks2 = 0; ks2 < 4; ++ks2)
      #pragma unroll
      for (int mi = 0; mi < 2; ++mi)
        #pragma unroll
        for (int ni = 0; ni < 2; ++ni)
          acc[mi][ni] = __builtin_amdgcn_mfma_f32_32x32x16_f16(af[mi][ks2], bf[ni][ks2], acc[mi][ni], 0, 0, 0);
    __builtin_amdgcn_s_barrier();   // all reads of buf[cur] done before re-stage
    cur ^= 1;
  }
#undef GSTAGE
  // epilogue: C/D layout col=lane&31, row=(reg&3)+8*(reg>>2)+4*(lane>>5)
  bool isx2 = (mt >= 32);
  int c = l & 31, r2 = l >> 5;
  #pragma unroll
  for (int ni = 0; ni < 2; ++ni) {
    int col = nt * 128 + wn * 64 + ni * 32 + c;
    float fvv = isx2 ? final_v[col] : 1.0f;
    #pragma unroll
    for (int mi = 0; mi < 2; ++mi) {
      int rowbase = mt * 128 + wm * 64 + mi * 32 + 4 * r2;
      #pragma unroll
      for (int r = 0; r < 16; ++r) {
        int row = rowbase + (r & 3) + 8 * (r >> 2);
        K16[(size_t)row * 1024 + col] = (f16)(fmaxf(acc[mi][ni][r], 0.f) * fvv);
      }
    }
  }
}

// ---------------- kernel 3: flash attention per (b, level, 64-row q tile) ----------------
// K/V double-buffered in LDS, ONE barrier per kt. Q direct global->reg.  [R12-verified]
__global__ void __launch_bounds__(256)
k_attn(const f16* __restrict__ K16, const f16* __restrict__ VT,
       const int* __restrict__ mask, float* __restrict__ out) {
  __shared__ f16 Klds[2 * 64 * 128];
  __shared__ f16 Vlds[2 * 128 * 64];
  __shared__ f16 Plds[4 * 16 * 64];
  __shared__ float bias[512];
  int bid = blockIdx.x;
  int qt = bid & 7, n = (bid >> 3) & 7, b = bid >> 6;
  int t = threadIdx.x, l = t & 63, w = t >> 6;
  for (int i = t; i < 512; i += 256) bias[i] = mask[b * 512 + i] ? -1e30f : 0.0f;
  int r4 = l >> 4;
  int slot = (l & 15) << 4;
  int lg = r4 << 4;
  const char* Kg = (const char*)K16 + ((size_t)(4096 + b * 512) * 1024 + n * 128) * 2;
  const char* Vg = (const char*)VT + (size_t)((b * 8 + n) * 128) * 1024;
  int vr = l >> 3;
  int vslot = (l & 7) << 4;

#define STAGE_KV(ktv, bufsel) do {                                              \
    _Pragma("unroll")                                                           \
    for (int i_ = 0; i_ < 4; ++i_) {                                            \
      int rl_ = w * 16 + i_ * 4 + r4;                                           \
      gload16(Kg + (size_t)((ktv) * 64 + rl_) * 2048 + (slot ^ ((rl_ & 7) << 4)), \
              (char*)Klds + (bufsel) * 16384 + (w * 16 + i_ * 4) * 256);        \
    }                                                                           \
    _Pragma("unroll")                                                           \
    for (int i_ = 0; i_ < 4; ++i_) {                                            \
      int dl_ = w * 32 + i_ * 8 + vr;                                           \
      gload16(Vg + (size_t)dl_ * 1024 + (ktv) * 128 + (vslot ^ ((dl_ & 7) << 4)), \
              (char*)Vlds + (bufsel) * 16384 + (w * 32 + i_ * 8) * 128);        \
    }                                                                           \
  } while (0)

  // Q fragments direct from global: frag kk = level-slice bytes [kk*64+lg, +16)
  const char* Qg = (const char*)K16 + ((size_t)(b * 512 + qt * 64) * 1024 + n * 128) * 2;
  int qrow = w * 16 + (l & 15);
  f16x8 qf[4];
  #pragma unroll
  for (int kk = 0; kk < 4; ++kk)
    qf[kk] = *(const f16x8*)(Qg + (size_t)qrow * 2048 + kk * 64 + lg);
  f32x4 o[8];
  #pragma unroll
  for (int dt = 0; dt < 8; ++dt) { o[dt][0] = 0.f; o[dt][1] = 0.f; o[dt][2] = 0.f; o[dt][3] = 0.f; }
  float m_r[4], l_r[4];
  #pragma unroll
  for (int r = 0; r < 4; ++r) { m_r[r] = -1e30f; l_r[r] = 0.0f; }
  char* Pw = (char*)Plds + w * 2048;

  STAGE_KV(0, 0);
  __syncthreads();  // drains stage(0); also orders bias[] init
  #pragma unroll 8
  for (int kt = 0; kt < 8; ++kt) {
    int cur = kt & 1;
    if (kt < 7) STAGE_KV(kt + 1, cur ^ 1);  // overlaps with compute below
    const char* Kl = (const char*)Klds + cur * 16384;
    const char* Vl = (const char*)Vlds + cur * 16384;
    f32x4 s[4];
    #pragma unroll
    for (int nt4 = 0; nt4 < 4; ++nt4) {
      s[nt4][0] = 0.f; s[nt4][1] = 0.f; s[nt4][2] = 0.f; s[nt4][3] = 0.f;
      int krow = nt4 * 16 + (l & 15);
      int ksz = (krow & 7) << 4;
      #pragma unroll
      for (int kk = 0; kk < 4; ++kk) {
        f16x8 kf = *(const f16x8*)(Kl + krow * 256 + ((kk * 64 + lg) ^ ksz));
        s[nt4] = __builtin_amdgcn_mfma_f32_16x16x32_f16(qf[kk], kf, s[nt4], 0, 0, 0);
      }
      float bc = bias[kt * 64 + nt4 * 16 + (l & 15)];
      #pragma unroll
      for (int r = 0; r < 4; ++r) s[nt4][r] += bc;
    }
    float pmax[4], scale[4], csum[4];
    #pragma unroll
    for (int r = 0; r < 4; ++r)
      pmax[r] = fmaxf(fmaxf(s[0][r], s[1][r]), fmaxf(s[2][r], s[3][r]));
    #pragma unroll
    for (int off = 1; off <= 8; off <<= 1) {
      #pragma unroll
      for (int r = 0; r < 4; ++r) pmax[r] = fmaxf(pmax[r], __shfl_xor(pmax[r], off));
    }
    #pragma unroll
    for (int r = 0; r < 4; ++r) {
      float mn = fmaxf(m_r[r], pmax[r]);
      scale[r] = __expf(m_r[r] - mn);
      m_r[r] = mn;
      csum[r] = 0.0f;
    }
    #pragma unroll
    for (int nt4 = 0; nt4 < 4; ++nt4) {
      #pragma unroll
      for (int r = 0; r < 4; ++r) {
        float sv = s[nt4][r];
        float p = (sv <= -1e29f) ? 0.0f : __expf(sv - m_r[r]);
        csum[r] += p;
        int prow = (r4 << 2) + r;
        int addr = prow * 128 + (((nt4 * 16 + (l & 15)) * 2) ^ ((prow & 7) << 4));
        *(f16*)(Pw + addr) = (f16)p;
      }
    }
    #pragma unroll
    for (int off = 1; off <= 8; off <<= 1) {
      #pragma unroll
      for (int r = 0; r < 4; ++r) csum[r] += __shfl_xor(csum[r], off);
    }
    #pragma unroll
    for (int r = 0; r < 4; ++r) l_r[r] = l_r[r] * scale[r] + csum[r];
    #pragma unroll
    for (int dt = 0; dt < 8; ++dt) {
      #pragma unroll
      for (int r = 0; r < 4; ++r) o[dt][r] *= scale[r];
    }
    asm volatile("s_waitcnt lgkmcnt(0)" ::: "memory");  // P writes visible to own-wave reads
    int prow = l & 15;
    int psz = (prow & 7) << 4;
    f16x8 pf0 = *(const f16x8*)((const char*)Pw + prow * 128 + (lg ^ psz));
    f16x8 pf1 = *(const f16x8*)((const char*)Pw + prow * 128 + ((lg + 64) ^ psz));
    #pragma unroll
    for (int dt = 0; dt < 8; ++dt) {
      int drow = dt * 16 + (l & 15);
      int dsz = (drow & 7) << 4;
      f16x8 vf0 = *(const f16x8*)(Vl + drow * 128 + (lg ^ dsz));
      f16x8 vf1 = *(const f16x8*)(Vl + drow * 128 + ((lg + 64) ^ dsz));
      o[dt] = __builtin_amdgcn_mfma_f32_16x16x32_f16(pf0, vf0, o[dt], 0, 0, 0);
      o[dt] = __builtin_amdgcn_mfma_f32_16x16x32_f16(pf1, vf1, o[dt], 0, 0, 0);
    }
    __syncthreads();
  }
#undef STAGE_KV
  size_t ob = (size_t)(b * 512 + qt * 64 + w * 16 + (r4 << 2)) * 1024 + n * 128 + (l & 15);
  #pragma unroll
  for (int r = 0; r < 4; ++r) {
    float inv = 1.0f / fmaxf(l_r[r], 1e-30f);
    #pragma unroll
    for (int dt = 0; dt < 8; ++dt)
      out[ob + (size_t)r * 1024 + dt * 16] = o[dt][r] * inv;
  }
}

extern "C" void kernel_launch(void* const* d_in, const int* in_sizes, int n_in,
                              void* d_out, int out_size, void* d_ws, size_t ws_size,
                              hipStream_t stream) {
  const float* x1a = (const float*)d_in[0];
  const float* x2a = (const float*)d_in[1];
  const float* x2  = (const float*)d_in[2];
  const int*   msk = (const int*)d_in[3];
  const float* W   = (const float*)d_in[4];
  const float* fv  = (const float*)d_in[5];
  float* out = (float*)d_out;
  if (ws_size < (size_t)WS_NEED) return;  // ws too small: fail loudly via unmodified (poisoned) d_out
  char* ws = (char*)d_ws;
  f16* A16 = (f16*)(ws + OFF_A16);
  f16* W16 = (f16*)(ws + OFF_W16);
  f16* K16 = (f16*)(ws + OFF_K16);
  f16* VT  = (f16*)(ws + OFF_VT);
  k_prep<<<2304, 256, 0, stream>>>(x1a, x2a, x2, W, A16, W16, VT);
  k_gemm_keys<<<512, 256, 0, stream>>>(A16, W16, fv, K16);
  k_attn<<<512, 256, 0, stream>>>(K16, VT, msk, out);
}

// Round 20
// 94.848 us; speedup vs baseline: 1.1467x; 1.0267x over previous
//
#include <hip/hip_runtime.h>
#include <stdint.h>

typedef _Float16 f16;
typedef _Float16 f16x8 __attribute__((ext_vector_type(8)));
typedef float f32x4 __attribute__((ext_vector_type(4)));
typedef float f32x16 __attribute__((ext_vector_type(16)));

typedef const __attribute__((address_space(1))) void* gas_ptr;
typedef __attribute__((address_space(3))) void* las_ptr;

__device__ __forceinline__ void gload16(const void* g, void* l) {
  __builtin_amdgcn_global_load_lds((gas_ptr)g, (las_ptr)l, 16, 0, 0);
}

// ws layout (bytes)
#define OFF_A16 0u              // [8192][2048] f16  (x1_att rows 0..4095, x2_att rows 4096..8191)
#define OFF_W16 33554432u       // [1024][2048] f16
#define OFF_K16 37748736u       // keys [8192][1024] f16
#define OFF_VT  54525952u       // V^T  [8][8][128][512] f16
#define WS_NEED 62914560u

// ---------------- kernel 1: prep = V^T transpose (blocks 0..255) + f32->f16 convert ----------------
__global__ void k_prep(const float* __restrict__ x1a, const float* __restrict__ x2a,
                       const float* __restrict__ x2, const float* __restrict__ W,
                       f16* __restrict__ A16, f16* __restrict__ W16, f16* __restrict__ VT) {
  __shared__ f16 T[128 * 130];  // used only by transpose blocks
  int t = threadIdx.x;
  if (blockIdx.x < 256) {
    // V^T: VT[((b*8+n)*128 + d)*512 + k] = (f16) x2[(b*512+k)*1024 + n*128 + d]
    int bid = blockIdx.x;
    int kt = bid & 3, n = (bid >> 2) & 7, b = bid >> 5;
    int k0 = kt * 128;
    #pragma unroll
    for (int p = 0; p < 16; ++p) {
      int kl = p * 8 + (t >> 5);
      int c4 = t & 31;
      float4 v = *(const float4*)(x2 + (size_t)(b * 512 + k0 + kl) * 1024 + n * 128 + c4 * 4);
      int d0 = c4 * 4;
      T[(d0 + 0) * 130 + kl] = (f16)v.x;
      T[(d0 + 1) * 130 + kl] = (f16)v.y;
      T[(d0 + 2) * 130 + kl] = (f16)v.z;
      T[(d0 + 3) * 130 + kl] = (f16)v.w;
    }
    __syncthreads();
    #pragma unroll
    for (int p = 0; p < 8; ++p) {
      int d = p * 16 + (t >> 4);
      int c = t & 15;
      f16x8 h;
      #pragma unroll
      for (int j = 0; j < 8; ++j) h[j] = T[d * 130 + c * 8 + j];
      *(f16x8*)(VT + (size_t)((b * 8 + n) * 128 + d) * 512 + k0 + c * 8) = h;
    }
    return;
  }
  // convert: 8 f32 -> 8 f16 per thread-iter, grid-stride over remaining blocks
  const int NA = (8192 * 2048) / 8;  // 2097152
  const int NH = NA / 2;
  const int NW = (1024 * 2048) / 8;  // 262144
  const int NT = NA + NW;
  int stride = (gridDim.x - 256) * blockDim.x;
  for (int g = (blockIdx.x - 256) * blockDim.x + t; g < NT; g += stride) {
    const float* src;
    f16* dst;
    if (g < NA) {
      src = (g < NH) ? (x1a + 8 * (size_t)g) : (x2a + 8 * (size_t)(g - NH));
      dst = A16 + 8 * (size_t)g;
    } else {
      src = W + 8 * (size_t)(g - NA);
      dst = W16 + 8 * (size_t)(g - NA);
    }
    float4 v0 = *(const float4*)src;
    float4 v1 = *(const float4*)(src + 4);
    f16x8 h;
    h[0] = (f16)v0.x; h[1] = (f16)v0.y; h[2] = (f16)v0.z; h[3] = (f16)v0.w;
    h[4] = (f16)v1.x; h[5] = (f16)v1.y; h[6] = (f16)v1.z; h[7] = (f16)v1.w;
    *(f16x8*)dst = h;
  }
}

// ---------------- kernel 2: keys = relu(A @ W^T) [*final_v for x2 rows] ----------------
// 128x128 tile, BK=128 (16 K-steps), 4 waves, 2x2 32x32x16 frags/wave.  [R10-verified]
// Row = 256B = 16 slots; swizzle slot' = slot ^ (row&15), within-row only.
// Best measured of 7 structural variants (43.3us, 0 bank conflicts); all
// pipelining attempts (dbuf R6, BK128-dbuf R18, counted-vmcnt R19) regressed.
__global__ void __launch_bounds__(256)
k_gemm_keys(const f16* __restrict__ A16, const f16* __restrict__ W16,
            const float* __restrict__ final_v, f16* __restrict__ K16) {
  __shared__ f16 Alds[128 * 128];
  __shared__ f16 Wlds[128 * 128];
  int bid = blockIdx.x;
  int sw = (bid & 7) * 64 + (bid >> 3);  // XCD swizzle (512 % 8 == 0, bijective)
  int mt = sw >> 3, nt = sw & 7;
  int t = threadIdx.x, l = t & 63, w = t >> 6;
  int wm = w >> 1, wn = w & 1;
  f32x16 acc[2][2];
  #pragma unroll
  for (int i = 0; i < 2; ++i)
    #pragma unroll
    for (int j = 0; j < 2; ++j)
      #pragma unroll
      for (int r = 0; r < 16; ++r) acc[i][j][r] = 0.f;
  const char* Ab = (const char*)A16 + (size_t)mt * 128 * 4096;
  const char* Wb = (const char*)W16 + (size_t)nt * 128 * 4096;
  size_t soff[8];
  #pragma unroll
  for (int i = 0; i < 8; ++i) {
    int row = (w * 8 + i) * 4 + (l >> 4);
    soff[i] = (size_t)row * 4096 + (((l & 15) ^ (row & 15)) << 4);
  }
  int g8 = l >> 5;
  int rowA = wm * 64 + (l & 31);
  int rowB = wn * 64 + (l & 31);
  int sA = rowA & 15, sB = rowB & 15;
  const char* rdA0 = (const char*)Alds + rowA * 256;
  const char* rdB0 = (const char*)Wlds + rowB * 256;
  for (int ks = 0; ks < 16; ++ks) {
    int k0b = ks * 256;  // 128 f16 = 256 bytes per step
    #pragma unroll
    for (int i = 0; i < 8; ++i) {
      gload16(Ab + soff[i] + k0b, (char*)Alds + (w * 8 + i) * 1024);
      gload16(Wb + soff[i] + k0b, (char*)Wlds + (w * 8 + i) * 1024);
    }
    __syncthreads();
    f16x8 af[2][8], bf[2][8];
    #pragma unroll
    for (int mi = 0; mi < 2; ++mi)
      #pragma unroll
      for (int ks2 = 0; ks2 < 8; ++ks2) {
        af[mi][ks2] = *(const f16x8*)(rdA0 + mi * 8192 + (((ks2 * 2 + g8) ^ sA) << 4));
        bf[mi][ks2] = *(const f16x8*)(rdB0 + mi * 8192 + (((ks2 * 2 + g8) ^ sB) << 4));
      }
    #pragma unroll
    for (int ks2 = 0; ks2 < 8; ++ks2)
      #pragma unroll
      for (int mi = 0; mi < 2; ++mi)
        #pragma unroll
        for (int ni = 0; ni < 2; ++ni)
          acc[mi][ni] = __builtin_amdgcn_mfma_f32_32x32x16_f16(af[mi][ks2], bf[ni][ks2], acc[mi][ni], 0, 0, 0);
    __syncthreads();
  }
  // epilogue: C/D layout col=lane&31, row=(reg&3)+8*(reg>>2)+4*(lane>>5)
  bool isx2 = (mt >= 32);
  int c = l & 31, r2 = l >> 5;
  #pragma unroll
  for (int ni = 0; ni < 2; ++ni) {
    int col = nt * 128 + wn * 64 + ni * 32 + c;
    float fvv = isx2 ? final_v[col] : 1.0f;
    #pragma unroll
    for (int mi = 0; mi < 2; ++mi) {
      int rowbase = mt * 128 + wm * 64 + mi * 32 + 4 * r2;
      #pragma unroll
      for (int r = 0; r < 16; ++r) {
        int row = rowbase + (r & 3) + 8 * (r >> 2);
        K16[(size_t)row * 1024 + col] = (f16)(fmaxf(acc[mi][ni][r], 0.f) * fvv);
      }
    }
  }
}

// ---------------- kernel 3: flash attention per (b, level, 64-row q tile) ----------------
// K/V double-buffered in LDS, ONE barrier per kt. Q direct global->reg.  [R12-verified]
__global__ void __launch_bounds__(256)
k_attn(const f16* __restrict__ K16, const f16* __restrict__ VT,
       const int* __restrict__ mask, float* __restrict__ out) {
  __shared__ f16 Klds[2 * 64 * 128];
  __shared__ f16 Vlds[2 * 128 * 64];
  __shared__ f16 Plds[4 * 16 * 64];
  __shared__ float bias[512];
  int bid = blockIdx.x;
  int qt = bid & 7, n = (bid >> 3) & 7, b = bid >> 6;
  int t = threadIdx.x, l = t & 63, w = t >> 6;
  for (int i = t; i < 512; i += 256) bias[i] = mask[b * 512 + i] ? -1e30f : 0.0f;
  int r4 = l >> 4;
  int slot = (l & 15) << 4;
  int lg = r4 << 4;
  const char* Kg = (const char*)K16 + ((size_t)(4096 + b * 512) * 1024 + n * 128) * 2;
  const char* Vg = (const char*)VT + (size_t)((b * 8 + n) * 128) * 1024;
  int vr = l >> 3;
  int vslot = (l & 7) << 4;

#define STAGE_KV(ktv, bufsel) do {                                              \
    _Pragma("unroll")                                                           \
    for (int i_ = 0; i_ < 4; ++i_) {                                            \
      int rl_ = w * 16 + i_ * 4 + r4;                                           \
      gload16(Kg + (size_t)((ktv) * 64 + rl_) * 2048 + (slot ^ ((rl_ & 7) << 4)), \
              (char*)Klds + (bufsel) * 16384 + (w * 16 + i_ * 4) * 256);        \
    }                                                                           \
    _Pragma("unroll")                                                           \
    for (int i_ = 0; i_ < 4; ++i_) {                                            \
      int dl_ = w * 32 + i_ * 8 + vr;                                           \
      gload16(Vg + (size_t)dl_ * 1024 + (ktv) * 128 + (vslot ^ ((dl_ & 7) << 4)), \
              (char*)Vlds + (bufsel) * 16384 + (w * 32 + i_ * 8) * 128);        \
    }                                                                           \
  } while (0)

  // Q fragments direct from global: frag kk = level-slice bytes [kk*64+lg, +16)
  const char* Qg = (const char*)K16 + ((size_t)(b * 512 + qt * 64) * 1024 + n * 128) * 2;
  int qrow = w * 16 + (l & 15);
  f16x8 qf[4];
  #pragma unroll
  for (int kk = 0; kk < 4; ++kk)
    qf[kk] = *(const f16x8*)(Qg + (size_t)qrow * 2048 + kk * 64 + lg);
  f32x4 o[8];
  #pragma unroll
  for (int dt = 0; dt < 8; ++dt) { o[dt][0] = 0.f; o[dt][1] = 0.f; o[dt][2] = 0.f; o[dt][3] = 0.f; }
  float m_r[4], l_r[4];
  #pragma unroll
  for (int r = 0; r < 4; ++r) { m_r[r] = -1e30f; l_r[r] = 0.0f; }
  char* Pw = (char*)Plds + w * 2048;

  STAGE_KV(0, 0);
  __syncthreads();  // drains stage(0); also orders bias[] init
  #pragma unroll 8
  for (int kt = 0; kt < 8; ++kt) {
    int cur = kt & 1;
    if (kt < 7) STAGE_KV(kt + 1, cur ^ 1);  // overlaps with compute below
    const char* Kl = (const char*)Klds + cur * 16384;
    const char* Vl = (const char*)Vlds + cur * 16384;
    f32x4 s[4];
    #pragma unroll
    for (int nt4 = 0; nt4 < 4; ++nt4) {
      s[nt4][0] = 0.f; s[nt4][1] = 0.f; s[nt4][2] = 0.f; s[nt4][3] = 0.f;
      int krow = nt4 * 16 + (l & 15);
      int ksz = (krow & 7) << 4;
      #pragma unroll
      for (int kk = 0; kk < 4; ++kk) {
        f16x8 kf = *(const f16x8*)(Kl + krow * 256 + ((kk * 64 + lg) ^ ksz));
        s[nt4] = __builtin_amdgcn_mfma_f32_16x16x32_f16(qf[kk], kf, s[nt4], 0, 0, 0);
      }
      float bc = bias[kt * 64 + nt4 * 16 + (l & 15)];
      #pragma unroll
      for (int r = 0; r < 4; ++r) s[nt4][r] += bc;
    }
    float pmax[4], scale[4], csum[4];
    #pragma unroll
    for (int r = 0; r < 4; ++r)
      pmax[r] = fmaxf(fmaxf(s[0][r], s[1][r]), fmaxf(s[2][r], s[3][r]));
    #pragma unroll
    for (int off = 1; off <= 8; off <<= 1) {
      #pragma unroll
      for (int r = 0; r < 4; ++r) pmax[r] = fmaxf(pmax[r], __shfl_xor(pmax[r], off));
    }
    #pragma unroll
    for (int r = 0; r < 4; ++r) {
      float mn = fmaxf(m_r[r], pmax[r]);
      scale[r] = __expf(m_r[r] - mn);
      m_r[r] = mn;
      csum[r] = 0.0f;
    }
    #pragma unroll
    for (int nt4 = 0; nt4 < 4; ++nt4) {
      #pragma unroll
      for (int r = 0; r < 4; ++r) {
        float sv = s[nt4][r];
        float p = (sv <= -1e29f) ? 0.0f : __expf(sv - m_r[r]);
        csum[r] += p;
        int prow = (r4 << 2) + r;
        int addr = prow * 128 + (((nt4 * 16 + (l & 15)) * 2) ^ ((prow & 7) << 4));
        *(f16*)(Pw + addr) = (f16)p;
      }
    }
    #pragma unroll
    for (int off = 1; off <= 8; off <<= 1) {
      #pragma unroll
      for (int r = 0; r < 4; ++r) csum[r] += __shfl_xor(csum[r], off);
    }
    #pragma unroll
    for (int r = 0; r < 4; ++r) l_r[r] = l_r[r] * scale[r] + csum[r];
    #pragma unroll
    for (int dt = 0; dt < 8; ++dt) {
      #pragma unroll
      for (int r = 0; r < 4; ++r) o[dt][r] *= scale[r];
    }
    asm volatile("s_waitcnt lgkmcnt(0)" ::: "memory");  // P writes visible to own-wave reads
    int prow = l & 15;
    int psz = (prow & 7) << 4;
    f16x8 pf0 = *(const f16x8*)((const char*)Pw + prow * 128 + (lg ^ psz));
    f16x8 pf1 = *(const f16x8*)((const char*)Pw + prow * 128 + ((lg + 64) ^ psz));
    #pragma unroll
    for (int dt = 0; dt < 8; ++dt) {
      int drow = dt * 16 + (l & 15);
      int dsz = (drow & 7) << 4;
      f16x8 vf0 = *(const f16x8*)(Vl + drow * 128 + (lg ^ dsz));
      f16x8 vf1 = *(const f16x8*)(Vl + drow * 128 + ((lg + 64) ^ dsz));
      o[dt] = __builtin_amdgcn_mfma_f32_16x16x32_f16(pf0, vf0, o[dt], 0, 0, 0);
      o[dt] = __builtin_amdgcn_mfma_f32_16x16x32_f16(pf1, vf1, o[dt], 0, 0, 0);
    }
    __syncthreads();
  }
#undef STAGE_KV
  size_t ob = (size_t)(b * 512 + qt * 64 + w * 16 + (r4 << 2)) * 1024 + n * 128 + (l & 15);
  #pragma unroll
  for (int r = 0; r < 4; ++r) {
    float inv = 1.0f / fmaxf(l_r[r], 1e-30f);
    #pragma unroll
    for (int dt = 0; dt < 8; ++dt)
      out[ob + (size_t)r * 1024 + dt * 16] = o[dt][r] * inv;
  }
}

extern "C" void kernel_launch(void* const* d_in, const int* in_sizes, int n_in,
                              void* d_out, int out_size, void* d_ws, size_t ws_size,
                              hipStream_t stream) {
  const float* x1a = (const float*)d_in[0];
  const float* x2a = (const float*)d_in[1];
  const float* x2  = (const float*)d_in[2];
  const int*   msk = (const int*)d_in[3];
  const float* W   = (const float*)d_in[4];
  const float* fv  = (const float*)d_in[5];
  float* out = (float*)d_out;
  if (ws_size < (size_t)WS_NEED) return;  // ws too small: fail loudly via unmodified (poisoned) d_out
  char* ws = (char*)d_ws;
  f16* A16 = (f16*)(ws + OFF_A16);
  f16* W16 = (f16*)(ws + OFF_W16);
  f16* K16 = (f16*)(ws + OFF_K16);
  f16* VT  = (f16*)(ws + OFF_VT);
  k_prep<<<2304, 256, 0, stream>>>(x1a, x2a, x2, W, A16, W16, VT);
  k_gemm_keys<<<512, 256, 0, stream>>>(A16, W16, fv, K16);
  k_attn<<<512, 256, 0, stream>>>(K16, VT, msk, out);
}